// Round 1
// baseline (110.572 us; speedup 1.0000x reference)
//
#include <hip/hip_runtime.h>
#include <hip/hip_bf16.h>

// DistMult edge score: out[e] = sum_d node_emb[src[e]][d] * rel_emb[e][d] * node_emb[dst[e]][d]
// N_NODES=100000, N_EDGES=1000000, DIM=64 (fp32).
//
// Strategy: 16 lanes per edge; each lane loads one float4 (16B) from each of
// head/rel/tail -> wave-contiguous 256B segments, perfectly coalesced.
// 4-step __shfl_xor reduce within the 16-lane group; lane 0 writes the score.
// Memory-bound: ~268 MB compulsory HBM traffic (rel_emb stream dominates);
// node_emb (25.6 MB) is L2/L3-resident for the gathers.

#define DIM 64
#define LANES_PER_EDGE 16

__global__ __launch_bounds__(256) void distmult_score_kernel(
    const float* __restrict__ node_emb,
    const float* __restrict__ rel_emb,
    const int* __restrict__ src,
    const int* __restrict__ dst,
    float* __restrict__ out,
    int n_edges)
{
    const int tid   = blockIdx.x * blockDim.x + threadIdx.x;
    const int lane  = tid & (LANES_PER_EDGE - 1);
    const int group = tid >> 4;
    const int n_groups = (gridDim.x * blockDim.x) >> 4;

    for (int e = group; e < n_edges; e += n_groups) {
        const int s = src[e];
        const int d = dst[e];

        const float4 r = *reinterpret_cast<const float4*>(rel_emb  + (size_t)e * DIM + lane * 4);
        const float4 h = *reinterpret_cast<const float4*>(node_emb + (size_t)s * DIM + lane * 4);
        const float4 t = *reinterpret_cast<const float4*>(node_emb + (size_t)d * DIM + lane * 4);

        float p = h.x * r.x * t.x
                + h.y * r.y * t.y
                + h.z * r.z * t.z
                + h.w * r.w * t.w;

        // Reduce across the 16 lanes of this edge's group.
        p += __shfl_xor(p, 1, 64);
        p += __shfl_xor(p, 2, 64);
        p += __shfl_xor(p, 4, 64);
        p += __shfl_xor(p, 8, 64);

        if (lane == 0) out[e] = p;
    }
}

extern "C" void kernel_launch(void* const* d_in, const int* in_sizes, int n_in,
                              void* d_out, int out_size, void* d_ws, size_t ws_size,
                              hipStream_t stream) {
    const float* node_emb = (const float*)d_in[0];
    const float* rel_emb  = (const float*)d_in[1];
    const int*   src      = (const int*)d_in[2];
    const int*   dst      = (const int*)d_in[3];
    float*       out      = (float*)d_out;

    const int n_edges = in_sizes[2];  // src has one entry per edge

    const int block = 256;
    // 16 lanes per edge -> total lanes = 16 * n_edges; cap grid and grid-stride.
    long long blocks_needed = ((long long)n_edges * LANES_PER_EDGE + block - 1) / block;
    int grid = (int)(blocks_needed < 2048 ? blocks_needed : 2048);

    distmult_score_kernel<<<grid, block, 0, stream>>>(node_emb, rel_emb, src, dst, out, n_edges);
}